// Round 11
// baseline (21.100 us; speedup 1.0000x reference)
//
#include <hip/hip_runtime.h>
#include <math.h>

#define TLEN 1024

typedef int i32x2 __attribute__((ext_vector_type(2)));

__device__ __forceinline__ float2 cadd(float2 a, float2 b){ return make_float2(a.x+b.x, a.y+b.y); }
__device__ __forceinline__ float2 csub(float2 a, float2 b){ return make_float2(a.x-b.x, a.y-b.y); }
__device__ __forceinline__ float2 cmul(float2 a, float2 b){
    return make_float2(fmaf(a.x, b.x, -(a.y*b.y)), fmaf(a.x, b.y, a.y*b.x));
}
__device__ __forceinline__ float2 cmulnegi(float2 a){ return make_float2(a.y, -a.x); }  // a * (-i)
__device__ __forceinline__ float2 cmulposi(float2 a){ return make_float2(-a.y, a.x); }  // a * (+i)
__device__ __forceinline__ int bitrev6(int l){
    return ((l & 1) << 5) | ((l & 2) << 3) | ((l & 4) << 1)
         | ((l & 8) >> 1) | ((l & 16) >> 3) | ((l & 32) >> 5);
}

// ---- cross-lane partner primitives (verified R4) ----
#define DPP_XOR1  0xB1   // quad_perm [1,0,3,2]
#define DPP_XOR2  0x4E   // quad_perm [2,3,0,1]
#define DPP_XOR8  0x128  // row_ror:8
#define SWZ_XOR4  0x101F // bitmode xor=4
#define SWZ_XOR16 0x401F // bitmode xor=16

template<int CTRL>
__device__ __forceinline__ float2 dpp2(float2 v){
    return make_float2(
        __int_as_float(__builtin_amdgcn_mov_dpp(__float_as_int(v.x), CTRL, 0xF, 0xF, false)),
        __int_as_float(__builtin_amdgcn_mov_dpp(__float_as_int(v.y), CTRL, 0xF, 0xF, false)));
}
template<int PAT>
__device__ __forceinline__ float2 swz2(float2 v){
    return make_float2(
        __int_as_float(__builtin_amdgcn_ds_swizzle(__float_as_int(v.x), PAT)),
        __int_as_float(__builtin_amdgcn_ds_swizzle(__float_as_int(v.y), PAT)));
}
__device__ __forceinline__ float p32f(float v, bool up){
#if __has_builtin(__builtin_amdgcn_permlane32_swap)
    i32x2 r = __builtin_amdgcn_permlane32_swap(__float_as_int(v), __float_as_int(v), false, false);
    return __int_as_float(up ? r[0] : r[1]);
#else
    int a = __float_as_int(v), b = __float_as_int(v);
    asm("v_permlane32_swap_b32 %0, %1" : "+v"(a), "+v"(b));
    return __int_as_float(up ? a : b);
#endif
}
__device__ __forceinline__ float2 p32_2(float2 v, bool up){
    return make_float2(p32f(v.x, up), p32f(v.y, up));
}

// DFT-4: y_k = sum_a x_a W4^{ak}
__device__ __forceinline__ void dft4(float2 x0, float2 x1, float2 x2, float2 x3,
                                     float2& y0, float2& y1, float2& y2, float2& y3){
    float2 t0 = cadd(x0, x2);
    float2 t1 = csub(x0, x2);
    float2 t2 = cadd(x1, x3);
    float2 t3 = csub(x1, x3);
    float2 n3 = cmulnegi(t3);
    y0 = cadd(t0, t2);
    y2 = csub(t0, t2);
    y1 = cadd(t1, n3);
    y3 = csub(t1, n3);
}

// selected output k of DFT-4 (k wave-uniform)
__device__ __forceinline__ float2 combine4(float2 x0, float2 x1, float2 x2, float2 x3, int k){
    float2 e = cadd(x0, x2), f = csub(x0, x2);
    float2 g = cadd(x1, x3), h = csub(x1, x3);
    if (k == 0) return cadd(e, g);
    if (k == 1) return cadd(f, cmulnegi(h));
    if (k == 2) return csub(e, g);
    return cadd(f, cmulposi(h));
}

// u[j] *= W16^{j*e}, e wave-uniform in [0,4)
__device__ __forceinline__ void tw16(float2 u[4], int e){
    const float C1 = 0.92387953251128675613f, S1 = 0.38268343236508977173f;
    const float H  = 0.70710678118654752440f;
    if (e == 1){
        u[1] = cmul(u[1], make_float2( C1, -S1));
        u[2] = cmul(u[2], make_float2(  H,  -H));
        u[3] = cmul(u[3], make_float2( S1, -C1));
    } else if (e == 2){
        u[1] = cmul(u[1], make_float2(  H,  -H));
        u[2] = cmulnegi(u[2]);
        u[3] = cmul(u[3], make_float2( -H,  -H));
    } else if (e == 3){
        u[1] = cmul(u[1], make_float2( S1, -C1));
        u[2] = cmul(u[2], make_float2( -H,  -H));
        u[3] = cmul(u[3], make_float2(-C1,  S1));
    }
}

// ---- cross-lane FFT-64 over lanes, 4 regs (verified R4/R8) ----
template<bool TW, typename F>
__device__ __forceinline__ void dif_stage4(float2 z[4], F partner, float sg, float2 w){
    #pragma unroll
    for (int r = 0; r < 4; ++r){
        float2 o = partner(z[r]);
        float2 pre = make_float2(fmaf(sg, z[r].x, o.x), fmaf(sg, z[r].y, o.y));
        z[r] = TW ? cmul(pre, w) : pre;
    }
}
template<bool TW, typename F>
__device__ __forceinline__ void dit_stage4(float2 z[4], F partner, float sg, float2 w){
    #pragma unroll
    for (int r = 0; r < 4; ++r){
        float2 zz = TW ? cmul(z[r], w) : z[r];
        float2 o = partner(zz);
        z[r] = make_float2(fmaf(sg, zz.x, o.x), fmaf(sg, zz.y, o.y));
    }
}
__device__ __forceinline__ void xfft_dif4(float2 z[4], const float2 Wt[5], int lane){
    const float2 ONE = make_float2(1.0f, 0.0f);
    {   const bool up = (lane & 32) != 0; const float sg = up ? -1.0f : 1.0f;
        dif_stage4<true>(z, [&](float2 v){ return p32_2(v, up); }, sg, up ? Wt[4] : ONE); }
    {   const bool up = (lane & 16) != 0; const float sg = up ? -1.0f : 1.0f;
        dif_stage4<true>(z, [](float2 v){ return swz2<SWZ_XOR16>(v); }, sg, up ? Wt[3] : ONE); }
    {   const bool up = (lane & 8) != 0;  const float sg = up ? -1.0f : 1.0f;
        dif_stage4<true>(z, [](float2 v){ return dpp2<DPP_XOR8>(v); }, sg, up ? Wt[2] : ONE); }
    {   const bool up = (lane & 4) != 0;  const float sg = up ? -1.0f : 1.0f;
        dif_stage4<true>(z, [](float2 v){ return swz2<SWZ_XOR4>(v); }, sg, up ? Wt[1] : ONE); }
    {   const bool up = (lane & 2) != 0;  const float sg = up ? -1.0f : 1.0f;
        dif_stage4<true>(z, [](float2 v){ return dpp2<DPP_XOR2>(v); }, sg, up ? Wt[0] : ONE); }
    {   const float sg = (lane & 1) ? -1.0f : 1.0f;
        dif_stage4<false>(z, [](float2 v){ return dpp2<DPP_XOR1>(v); }, sg, ONE); }
}
__device__ __forceinline__ void xfft_dit4(float2 z[4], const float2 Wt[5], int lane){
    const float2 ONE = make_float2(1.0f, 0.0f);
    {   const float sg = (lane & 1) ? -1.0f : 1.0f;
        dit_stage4<false>(z, [](float2 v){ return dpp2<DPP_XOR1>(v); }, sg, ONE); }
    {   const bool up = (lane & 2) != 0;  const float sg = up ? -1.0f : 1.0f;
        dit_stage4<true>(z, [](float2 v){ return dpp2<DPP_XOR2>(v); }, sg, up ? Wt[0] : ONE); }
    {   const bool up = (lane & 4) != 0;  const float sg = up ? -1.0f : 1.0f;
        dit_stage4<true>(z, [](float2 v){ return swz2<SWZ_XOR4>(v); }, sg, up ? Wt[1] : ONE); }
    {   const bool up = (lane & 8) != 0;  const float sg = up ? -1.0f : 1.0f;
        dit_stage4<true>(z, [](float2 v){ return dpp2<DPP_XOR8>(v); }, sg, up ? Wt[2] : ONE); }
    {   const bool up = (lane & 16) != 0; const float sg = up ? -1.0f : 1.0f;
        dit_stage4<true>(z, [](float2 v){ return swz2<SWZ_XOR16>(v); }, sg, up ? Wt[3] : ONE); }
    {   const bool up = (lane & 32) != 0; const float sg = up ? -1.0f : 1.0f;
        dit_stage4<true>(z, [&](float2 v){ return p32_2(v, up); }, sg, up ? Wt[4] : ONE); }
}

// ============================================================================
// fused v3: waves 4-7 PRODUCE phasor tables for layers 4..0 into LDS before
// the chain's first barrier; chain (waves 0-3) consumes them from LDS instead
// of 20 serial __sincosf. Layers 0/2/4 stored transposed (conflict-free
// lane-consecutive reads); layers 1/3 natural. 6 barriers on both paths.
// ============================================================================
__global__ __launch_bounds__(512, 4)
void fused_kernel(const float* __restrict__ X,
                  const float* __restrict__ W,
                  float* __restrict__ out)
{
    __shared__ float2 tblE[3 * TLEN];  // layers 0,2,4 transposed: [le][o*64+q], o=t&15,q=t>>4  (24 KiB)
    __shared__ float2 tblO[2 * TLEN];  // layers 1,3 natural: [lo][t]                           (16 KiB)
    __shared__ float2 xb0[16 * 64];    // exchange buffer A (8 KiB)
    __shared__ float2 xb1[16 * 64];    // exchange buffer B / final a (8 KiB)

    const int lane = threadIdx.x & 63;
    const int wid  = threadIdx.x >> 6;   // 0..7
    const int row  = blockIdx.x * 8 + wid;

    // ---- prefetch own row of X (no wait until dot phase) ----
    float4 xr[4];
    {
        const float4* px = (const float4*)(X + (size_t)row * TLEN + lane * 16);
        #pragma unroll
        for (int i = 0; i < 4; ++i) xr[i] = px[i];
    }

    if (wid < 4){
        // ================= prep chain (waves 0-3) =================
        const int c = bitrev6(lane);
        float2 Wt[5];
        #pragma unroll
        for (int k = 0; k < 5; ++k){
            const int h = 2 << k;
            float sv, cv;
            __sincosf(-3.14159265358979323846f * (float)(lane & (h - 1)) / (float)h, &sv, &cv);
            Wt[k] = make_float2(cv, sv);
        }
        float2 wmv[4];
        {
            const float theta = -6.28318530717958647692f * (float)c / 1024.0f;
            float sv, cv;
            __sincosf(theta * (float)(4 * wid), &sv, &cv); float2 base = make_float2(cv, sv);
            __sincosf(theta, &sv, &cv);                    float2 step = make_float2(cv, sv);
            wmv[0] = base;
            wmv[1] = cmul(wmv[0], step);
            wmv[2] = cmul(wmv[1], step);
            wmv[3] = cmul(wmv[2], step);
        }

        float2 z[4];
        #pragma unroll
        for (int j = 0; j < 4; ++j) z[j] = make_float2(1.0f, 0.0f);  // F e0 (uniform)

        auto Mstr = [&](){
            const bool upm = (lane & 32) != 0;
            const float sgm = upm ? -1.0f : 1.0f;
            #pragma unroll
            for (int j = 0; j < 4; ++j){
                float2 o = p32_2(z[j], upm);
                z[j] = make_float2(fmaf(sgm, z[j].x, o.x), fmaf(sgm, z[j].y, o.y));
            }
        };
        auto Mcon = [&](){
            float2 a0 = z[0], b0 = z[1], a1 = z[2], b1 = z[3];
            z[0] = cadd(a0, b0); z[1] = csub(a0, b0);
            z[2] = cadd(a1, b1); z[3] = csub(a1, b1);
        };
        // layer 5 only: computed via sincos (needed before any barrier)
        auto DstrSin = [&](int l){  // t = 64*(wid + 4j) + c
            const float* p = W + l * TLEN + c + 64 * wid;
            #pragma unroll
            for (int j = 0; j < 4; ++j){
                float sv, cv; __sincosf(p[j << 8], &sv, &cv);
                z[j] = cmul(z[j], make_float2(cv, sv));
            }
        };
        // layers 3,1 from LDS table (natural layout); reads AFTER a barrier
        auto Dstr = [&](int l){  // t = 64*(wid + 4j) + c
            const float2* p = tblO + ((l - 1) >> 1) * TLEN + 64 * wid + c;
            #pragma unroll
            for (int j = 0; j < 4; ++j) z[j] = cmul(z[j], p[j << 8]);
        };
        // layers 4,2,0 from LDS table (transposed layout, conflict-free)
        auto Dcon = [&](int l){  // t = 16*lane + 4*wid + j -> tblE[le][(4wid+j)*64 + lane]
            const float2* p = tblE + (l >> 1) * TLEN + (4 * wid) * 64 + lane;
            #pragma unroll
            for (int j = 0; j < 4; ++j) z[j] = cmul(z[j], p[j << 6]);
        };
        auto midtw = [&](){
            #pragma unroll
            for (int j = 0; j < 4; ++j) z[j] = cmul(z[j], wmv[j]);
        };
        // FFT-16 over r, input (w,j) holds r = 4w+j -> output (w,j) holds X[w+4j]
        auto fft16A = [&](){
            #pragma unroll
            for (int j = 0; j < 4; ++j) xb1[(wid * 4 + j) * 64 + lane] = z[j];
            __syncthreads();
            float2 u[4];
            #pragma unroll
            for (int j = 0; j < 4; ++j){
                float2 x0 = xb1[(0 * 4 + j) * 64 + lane];
                float2 x1 = xb1[(1 * 4 + j) * 64 + lane];
                float2 x2 = xb1[(2 * 4 + j) * 64 + lane];
                float2 x3 = xb1[(3 * 4 + j) * 64 + lane];
                u[j] = combine4(x0, x1, x2, x3, wid);
            }
            tw16(u, wid);
            dft4(u[0], u[1], u[2], u[3], z[0], z[1], z[2], z[3]);
        };
        // FFT-16 over r, input (w,j) holds r = w+4j -> output (w,j) holds X[4w+j]
        auto fft16B = [&](){
            float2 u[4];
            dft4(z[0], z[1], z[2], z[3], u[0], u[1], u[2], u[3]);
            tw16(u, wid);
            #pragma unroll
            for (int j = 0; j < 4; ++j) xb0[(wid * 4 + j) * 64 + lane] = u[j];
            __syncthreads();
            #pragma unroll
            for (int j = 0; j < 4; ++j){
                float2 x0 = xb0[(0 * 4 + j) * 64 + lane];
                float2 x1 = xb0[(1 * 4 + j) * 64 + lane];
                float2 x2 = xb0[(2 * 4 + j) * 64 + lane];
                float2 x3 = xb0[(3 * 4 + j) * 64 + lane];
                z[j] = combine4(x0, x1, x2, x3, wid);
            }
        };
        auto dftA = [&](){ xfft_dif4(z, Wt, lane); midtw(); fft16A(); };
        auto dftB = [&](){ fft16B(); midtw(); xfft_dit4(z, Wt, lane); };

        // chain: v = e0; for l=5..0: v = D_l M F v.  (F#1 folded into init)
        Mstr(); DstrSin(5);
        #pragma unroll 1
        for (int lp = 0; lp < 2; ++lp){
            dftB(); Mcon(); Dcon(4 - 2 * lp);   // barrier 1,3; table read after it
            dftA(); Mstr(); Dstr(3 - 2 * lp);   // barrier 2,4
        }
        dftB(); Mcon(); Dcon(0);                // barrier 5
        // store a transposed into xb1: a[16*l + 4*wid + j] -> xb1[(4*wid+j)*64 + l]
        #pragma unroll
        for (int j = 0; j < 4; ++j) xb1[(4 * wid + j) * 64 + lane] = z[j];
        __syncthreads();                        // barrier 6
    } else {
        // ============ producer waves 4-7: phasor tables, then 6 barriers ============
        const int pt = threadIdx.x - 256;  // 0..255
        // layers 0,2,4 transposed: coalesced W reads, scattered LDS writes
        #pragma unroll 1
        for (int i = pt; i < 3 * TLEN; i += 256){
            int le = i >> 10, t = i & 1023;
            float sv, cv; __sincosf(W[2 * le * TLEN + t], &sv, &cv);
            tblE[le * TLEN + ((t & 15) << 6) + (t >> 4)] = make_float2(cv, sv);
        }
        // layers 1,3 natural
        #pragma unroll 1
        for (int i = pt; i < 2 * TLEN; i += 256){
            int lo = i >> 10, t = i & 1023;
            float sv, cv; __sincosf(W[(2 * lo + 1) * TLEN + t], &sv, &cv);
            tblO[i] = make_float2(cv, sv);
        }
        #pragma unroll 1
        for (int b = 0; b < 6; ++b) __syncthreads();
    }

    // ================= dot phase: every wave its own row =================
    float re = 0.0f, im = 0.0f;
    #pragma unroll
    for (int i = 0; i < 4; ++i){
        float4 xv = xr[i];
        float xs[4] = {xv.x, xv.y, xv.z, xv.w};
        #pragma unroll
        for (int j = 0; j < 4; ++j){
            float2 av = xb1[(4 * i + j) * 64 + lane];   // a[16*lane + 4i + j]
            float x  = fminf(fmaxf(xs[j], -0.999f), 0.999f);
            float cc = sqrtf(fmaf(-x, x, 1.0f));
            re = fmaf(av.x, cc, re);  re = fmaf(-av.y, x,  re);
            im = fmaf(av.x, x,  im);  im = fmaf( av.y, cc, im);
        }
    }

    float2 s = make_float2(re, im);
    s = cadd(s, dpp2<DPP_XOR1>(s));
    s = cadd(s, dpp2<DPP_XOR2>(s));
    s = cadd(s, swz2<SWZ_XOR4>(s));
    s = cadd(s, dpp2<DPP_XOR8>(s));
    s = cadd(s, swz2<SWZ_XOR16>(s));
    s = cadd(s, p32_2(s, (lane & 32) != 0));

    if (lane == 0){
        out[row] = fmaf(s.y * rsqrtf(fmaf(s.x, s.x, s.y * s.y)), 0.5f, 0.5f);
    }
}

extern "C" void kernel_launch(void* const* d_in, const int* in_sizes, int n_in,
                              void* d_out, int out_size, void* d_ws, size_t ws_size,
                              hipStream_t stream) {
    const float* X = (const float*)d_in[0];   // [4096, 1024]
    const float* W = (const float*)d_in[1];   // [6*1024]
    float* out = (float*)d_out;               // [4096]
    (void)in_sizes; (void)n_in; (void)out_size; (void)d_ws; (void)ws_size;

    fused_kernel<<<4096 / 8, 512, 0, stream>>>(X, W, out);
}

// Round 12
// 17.472 us; speedup vs baseline: 1.2076x; 1.2076x over previous
//
#include <hip/hip_runtime.h>
#include <math.h>

#define TLEN 1024

typedef int i32x2 __attribute__((ext_vector_type(2)));

__device__ __forceinline__ float2 cadd(float2 a, float2 b){ return make_float2(a.x+b.x, a.y+b.y); }
__device__ __forceinline__ float2 csub(float2 a, float2 b){ return make_float2(a.x-b.x, a.y-b.y); }
__device__ __forceinline__ float2 cmul(float2 a, float2 b){
    return make_float2(fmaf(a.x, b.x, -(a.y*b.y)), fmaf(a.x, b.y, a.y*b.x));
}
__device__ __forceinline__ float2 cmulnegi(float2 a){ return make_float2(a.y, -a.x); }  // a * (-i)
__device__ __forceinline__ float2 cmulposi(float2 a){ return make_float2(-a.y, a.x); }  // a * (+i)
__device__ __forceinline__ int bitrev6(int l){
    return ((l & 1) << 5) | ((l & 2) << 3) | ((l & 4) << 1)
         | ((l & 8) >> 1) | ((l & 16) >> 3) | ((l & 32) >> 5);
}

// ---- cross-lane partner primitives (verified R4) ----
#define DPP_XOR1  0xB1   // quad_perm [1,0,3,2]
#define DPP_XOR2  0x4E   // quad_perm [2,3,0,1]
#define DPP_XOR8  0x128  // row_ror:8
#define SWZ_XOR4  0x101F // bitmode xor=4
#define SWZ_XOR16 0x401F // bitmode xor=16

template<int CTRL>
__device__ __forceinline__ float2 dpp2(float2 v){
    return make_float2(
        __int_as_float(__builtin_amdgcn_mov_dpp(__float_as_int(v.x), CTRL, 0xF, 0xF, false)),
        __int_as_float(__builtin_amdgcn_mov_dpp(__float_as_int(v.y), CTRL, 0xF, 0xF, false)));
}
template<int PAT>
__device__ __forceinline__ float2 swz2(float2 v){
    return make_float2(
        __int_as_float(__builtin_amdgcn_ds_swizzle(__float_as_int(v.x), PAT)),
        __int_as_float(__builtin_amdgcn_ds_swizzle(__float_as_int(v.y), PAT)));
}
__device__ __forceinline__ float p32f(float v, bool up){
#if __has_builtin(__builtin_amdgcn_permlane32_swap)
    i32x2 r = __builtin_amdgcn_permlane32_swap(__float_as_int(v), __float_as_int(v), false, false);
    return __int_as_float(up ? r[0] : r[1]);
#else
    int a = __float_as_int(v), b = __float_as_int(v);
    asm("v_permlane32_swap_b32 %0, %1" : "+v"(a), "+v"(b));
    return __int_as_float(up ? a : b);
#endif
}
__device__ __forceinline__ float2 p32_2(float2 v, bool up){
    return make_float2(p32f(v.x, up), p32f(v.y, up));
}

// selected output k of DFT-4 (k wave-uniform)
__device__ __forceinline__ float2 combine4(float2 x0, float2 x1, float2 x2, float2 x3, int k){
    float2 e = cadd(x0, x2), f = csub(x0, x2);
    float2 g = cadd(x1, x3), h = csub(x1, x3);
    if (k == 0) return cadd(e, g);
    if (k == 1) return cadd(f, cmulnegi(h));
    if (k == 2) return csub(e, g);
    return cadd(f, cmulposi(h));
}
// selected output k of DFT-8 (k wave-uniform): y_k = E_{k&3} +/- W8^{k&3} O_{k&3}
__device__ __forceinline__ float2 combine8(const float2 x[8], int k){
    const float H = 0.70710678118654752440f;
    float2 E = combine4(x[0], x[2], x[4], x[6], k & 3);
    float2 O = combine4(x[1], x[3], x[5], x[7], k & 3);
    float2 WO;
    switch (k & 3){
        case 0:  WO = O; break;
        case 1:  WO = cmul(O, make_float2( H, -H)); break;
        case 2:  WO = cmulnegi(O); break;
        default: WO = cmul(O, make_float2(-H, -H)); break;
    }
    return (k < 4) ? cadd(E, WO) : csub(E, WO);
}

// ---- cross-lane FFT-64 over lanes, 2 regs (structure verified R4/R8) ----
template<bool TW, typename F>
__device__ __forceinline__ void dif_stage2(float2 z[2], F partner, float sg, float2 w){
    #pragma unroll
    for (int r = 0; r < 2; ++r){
        float2 o = partner(z[r]);
        float2 pre = make_float2(fmaf(sg, z[r].x, o.x), fmaf(sg, z[r].y, o.y));
        z[r] = TW ? cmul(pre, w) : pre;
    }
}
template<bool TW, typename F>
__device__ __forceinline__ void dit_stage2(float2 z[2], F partner, float sg, float2 w){
    #pragma unroll
    for (int r = 0; r < 2; ++r){
        float2 zz = TW ? cmul(z[r], w) : z[r];
        float2 o = partner(zz);
        z[r] = make_float2(fmaf(sg, zz.x, o.x), fmaf(sg, zz.y, o.y));
    }
}
__device__ __forceinline__ void xfft_dif2(float2 z[2], const float2 Wt[5], int lane){
    const float2 ONE = make_float2(1.0f, 0.0f);
    {   const bool up = (lane & 32) != 0; const float sg = up ? -1.0f : 1.0f;
        dif_stage2<true>(z, [&](float2 v){ return p32_2(v, up); }, sg, up ? Wt[4] : ONE); }
    {   const bool up = (lane & 16) != 0; const float sg = up ? -1.0f : 1.0f;
        dif_stage2<true>(z, [](float2 v){ return swz2<SWZ_XOR16>(v); }, sg, up ? Wt[3] : ONE); }
    {   const bool up = (lane & 8) != 0;  const float sg = up ? -1.0f : 1.0f;
        dif_stage2<true>(z, [](float2 v){ return dpp2<DPP_XOR8>(v); }, sg, up ? Wt[2] : ONE); }
    {   const bool up = (lane & 4) != 0;  const float sg = up ? -1.0f : 1.0f;
        dif_stage2<true>(z, [](float2 v){ return swz2<SWZ_XOR4>(v); }, sg, up ? Wt[1] : ONE); }
    {   const bool up = (lane & 2) != 0;  const float sg = up ? -1.0f : 1.0f;
        dif_stage2<true>(z, [](float2 v){ return dpp2<DPP_XOR2>(v); }, sg, up ? Wt[0] : ONE); }
    {   const float sg = (lane & 1) ? -1.0f : 1.0f;
        dif_stage2<false>(z, [](float2 v){ return dpp2<DPP_XOR1>(v); }, sg, ONE); }
}
__device__ __forceinline__ void xfft_dit2(float2 z[2], const float2 Wt[5], int lane){
    const float2 ONE = make_float2(1.0f, 0.0f);
    {   const float sg = (lane & 1) ? -1.0f : 1.0f;
        dit_stage2<false>(z, [](float2 v){ return dpp2<DPP_XOR1>(v); }, sg, ONE); }
    {   const bool up = (lane & 2) != 0;  const float sg = up ? -1.0f : 1.0f;
        dit_stage2<true>(z, [](float2 v){ return dpp2<DPP_XOR2>(v); }, sg, up ? Wt[0] : ONE); }
    {   const bool up = (lane & 4) != 0;  const float sg = up ? -1.0f : 1.0f;
        dit_stage2<true>(z, [](float2 v){ return swz2<SWZ_XOR4>(v); }, sg, up ? Wt[1] : ONE); }
    {   const bool up = (lane & 8) != 0;  const float sg = up ? -1.0f : 1.0f;
        dit_stage2<true>(z, [](float2 v){ return dpp2<DPP_XOR8>(v); }, sg, up ? Wt[2] : ONE); }
    {   const bool up = (lane & 16) != 0; const float sg = up ? -1.0f : 1.0f;
        dit_stage2<true>(z, [](float2 v){ return swz2<SWZ_XOR16>(v); }, sg, up ? Wt[3] : ONE); }
    {   const bool up = (lane & 32) != 0; const float sg = up ? -1.0f : 1.0f;
        dit_stage2<true>(z, [&](float2 v){ return p32_2(v, up); }, sg, up ? Wt[4] : ONE); }
}

// ============================================================================
// fused v4: 8-wave chain. 16 regs split r = 2*wid + j (j<2) across all 8
// waves; FFT-16 over r = FFT-8(cross-wave via LDS combine8) x FFT-2(in-reg).
// Every wave runs the chain AND dots its own row; 6 barriers, no spinning.
// ============================================================================
__global__ __launch_bounds__(512, 4)
void fused_kernel(const float* __restrict__ X,
                  const float* __restrict__ W,
                  float* __restrict__ out)
{
    __shared__ float2 xb0[16 * 64];    // exchange buffer A (8 KiB)
    __shared__ float2 xb1[16 * 64];    // exchange buffer B / final a (8 KiB)

    const int lane = threadIdx.x & 63;
    const int wid  = threadIdx.x >> 6;   // 0..7
    const int row  = blockIdx.x * 8 + wid;

    // ---- prefetch own row of X (no wait until dot phase) ----
    float4 xr[4];
    {
        const float4* px = (const float4*)(X + (size_t)row * TLEN + lane * 16);
        #pragma unroll
        for (int i = 0; i < 4; ++i) xr[i] = px[i];
    }

    // ================= prep chain (all 8 waves) =================
    const int c = bitrev6(lane);
    float2 Wt[5];
    #pragma unroll
    for (int k = 0; k < 5; ++k){
        const int h = 2 << k;
        float sv, cv;
        __sincosf(-3.14159265358979323846f * (float)(lane & (h - 1)) / (float)h, &sv, &cv);
        Wt[k] = make_float2(cv, sv);
    }
    // W16^{wid} (wave-uniform)
    float2 w16;
    {
        float sv, cv;
        __sincosf(-3.14159265358979323846f * (float)wid / 8.0f, &sv, &cv);
        w16 = make_float2(cv, sv);
    }
    // mid twiddles wmv[j] = W1024^{c*(2*wid+j)}
    float2 wmv[2];
    {
        const float theta = -6.28318530717958647692f * (float)c / 1024.0f;
        float sv, cv;
        __sincosf(theta * (float)(2 * wid), &sv, &cv); wmv[0] = make_float2(cv, sv);
        __sincosf(theta, &sv, &cv);                    wmv[1] = cmul(wmv[0], make_float2(cv, sv));
    }

    float2 z[2];
    z[0] = make_float2(1.0f, 0.0f);   // F e0 (uniform)
    z[1] = make_float2(1.0f, 0.0f);

    auto Mstr = [&](){   // strided: partner flips c bit0 = lane bit5
        const bool upm = (lane & 32) != 0;
        const float sgm = upm ? -1.0f : 1.0f;
        #pragma unroll
        for (int j = 0; j < 2; ++j){
            float2 o = p32_2(z[j], upm);
            z[j] = make_float2(fmaf(sgm, z[j].x, o.x), fmaf(sgm, z[j].y, o.y));
        }
    };
    auto Mcon = [&](){   // consecutive: pair is (j=0, j=1)
        float2 a0 = z[0], b0 = z[1];
        z[0] = cadd(a0, b0); z[1] = csub(a0, b0);
    };
    auto Dstr = [&](int l){  // t = 64*(wid + 8j) + c
        const float* p = W + l * TLEN + c + 64 * wid;
        #pragma unroll
        for (int j = 0; j < 2; ++j){
            float sv, cv; __sincosf(p[j << 9], &sv, &cv);
            z[j] = cmul(z[j], make_float2(cv, sv));
        }
    };
    auto Dcon = [&](int l){  // t = 16*lane + 2*wid + j
        float2 wv = *(const float2*)(W + l * TLEN + 16 * lane + 2 * wid);
        float ws[2] = {wv.x, wv.y};
        #pragma unroll
        for (int j = 0; j < 2; ++j){
            float sv, cv; __sincosf(ws[j], &sv, &cv);
            z[j] = cmul(z[j], make_float2(cv, sv));
        }
    };
    auto midtw = [&](){
        z[0] = cmul(z[0], wmv[0]);
        z[1] = cmul(z[1], wmv[1]);
    };
    // FFT-16 over r, input (w,j) holds r = 2w+j -> output (w,j) holds X16[w+8j]
    auto fft16A = [&](){
        #pragma unroll
        for (int j = 0; j < 2; ++j) xb1[(wid * 2 + j) * 64 + lane] = z[j];
        __syncthreads();
        float2 u[2];
        #pragma unroll
        for (int j = 0; j < 2; ++j){
            float2 x[8];
            #pragma unroll
            for (int w = 0; w < 8; ++w) x[w] = xb1[(2 * w + j) * 64 + lane];
            u[j] = combine8(x, wid);      // k1 = wid
        }
        u[1] = cmul(u[1], w16);           // W16^{j*k1}
        z[0] = cadd(u[0], u[1]);          // FFT-2 over j -> k2
        z[1] = csub(u[0], u[1]);
    };
    // FFT-16 over r, input (w,j) holds r = w+8j -> output (w,j) holds X16[2w+j]
    auto fft16B = [&](){
        float2 u[2];
        u[0] = cadd(z[0], z[1]);          // FFT-2 over j -> k_lo
        u[1] = csub(z[0], z[1]);
        u[1] = cmul(u[1], w16);           // W16^{w*k_lo}
        #pragma unroll
        for (int j = 0; j < 2; ++j) xb0[(wid * 2 + j) * 64 + lane] = u[j];
        __syncthreads();
        #pragma unroll
        for (int j = 0; j < 2; ++j){
            float2 x[8];
            #pragma unroll
            for (int w = 0; w < 8; ++w) x[w] = xb0[(2 * w + j) * 64 + lane];
            z[j] = combine8(x, wid);      // k1 = wid -> X16[j + 2*wid]
        }
    };
    auto dftA = [&](){ xfft_dif2(z, Wt, lane); midtw(); fft16A(); };
    auto dftB = [&](){ fft16B(); midtw(); xfft_dit2(z, Wt, lane); };

    // chain: v = e0; for l=5..0: v = D_l M F v.  (F#1 folded into init)
    Mstr(); Dstr(5);
    #pragma unroll 1
    for (int lp = 0; lp < 2; ++lp){
        dftB(); Mcon(); Dcon(4 - 2 * lp);   // barrier 1,3
        dftA(); Mstr(); Dstr(3 - 2 * lp);   // barrier 2,4
    }
    dftB(); Mcon(); Dcon(0);                // barrier 5
    // store a (consecutive layout): a[16*lane + 2*wid + j] -> xb1[(2*wid+j)*64 + lane]
    #pragma unroll
    for (int j = 0; j < 2; ++j) xb1[(2 * wid + j) * 64 + lane] = z[j];
    __syncthreads();                        // barrier 6

    // ================= dot phase: every wave its own row =================
    float re = 0.0f, im = 0.0f;
    #pragma unroll
    for (int i = 0; i < 4; ++i){
        float4 xv = xr[i];
        float xs[4] = {xv.x, xv.y, xv.z, xv.w};
        #pragma unroll
        for (int j = 0; j < 4; ++j){
            float2 av = xb1[(4 * i + j) * 64 + lane];   // a[16*lane + 4i + j]
            float x  = fminf(fmaxf(xs[j], -0.999f), 0.999f);
            float cc = sqrtf(fmaf(-x, x, 1.0f));
            re = fmaf(av.x, cc, re);  re = fmaf(-av.y, x,  re);
            im = fmaf(av.x, x,  im);  im = fmaf( av.y, cc, im);
        }
    }

    float2 s = make_float2(re, im);
    s = cadd(s, dpp2<DPP_XOR1>(s));
    s = cadd(s, dpp2<DPP_XOR2>(s));
    s = cadd(s, swz2<SWZ_XOR4>(s));
    s = cadd(s, dpp2<DPP_XOR8>(s));
    s = cadd(s, swz2<SWZ_XOR16>(s));
    s = cadd(s, p32_2(s, (lane & 32) != 0));

    if (lane == 0){
        out[row] = fmaf(s.y * rsqrtf(fmaf(s.x, s.x, s.y * s.y)), 0.5f, 0.5f);
    }
}

extern "C" void kernel_launch(void* const* d_in, const int* in_sizes, int n_in,
                              void* d_out, int out_size, void* d_ws, size_t ws_size,
                              hipStream_t stream) {
    const float* X = (const float*)d_in[0];   // [4096, 1024]
    const float* W = (const float*)d_in[1];   // [6*1024]
    float* out = (float*)d_out;               // [4096]
    (void)in_sizes; (void)n_in; (void)out_size; (void)d_ws; (void)ws_size;

    fused_kernel<<<4096 / 8, 512, 0, stream>>>(X, W, out);
}